// Round 5
// baseline (375.852 us; speedup 1.0000x reference)
//
#include <hip/hip_runtime.h>
#include <math.h>

#define BB 64
#define DD 512
#define MM 8192
#define NT 256   // k2 threads: 4 waves

typedef unsigned long long u64;

// ---------------- DPP wave-64 primitives (row_shr prefix + row_bcast) ----------------
template<int CTRL>
__device__ __forceinline__ float dpp_addf(float x) {
    int y = __builtin_amdgcn_update_dpp(0, __float_as_int(x), CTRL, 0xF, 0xF, true);
    return x + __int_as_float(y);
}
__device__ __forceinline__ float wave_sum64(float x) {
    x = dpp_addf<0x111>(x); x = dpp_addf<0x112>(x); x = dpp_addf<0x114>(x); x = dpp_addf<0x118>(x);
    x = dpp_addf<0x142>(x); x = dpp_addf<0x143>(x);
    return __int_as_float(__builtin_amdgcn_readlane(__float_as_int(x), 63));
}
template<int CTRL>
__device__ __forceinline__ u64 dpp_min_step(u64 k) {
    unsigned lo = (unsigned)k, hi = (unsigned)(k >> 32);
    unsigned nlo = (unsigned)__builtin_amdgcn_update_dpp((int)0xFFFFFFFFu, (int)lo, CTRL, 0xF, 0xF, false);
    unsigned nhi = (unsigned)__builtin_amdgcn_update_dpp((int)0xFFFFFFFFu, (int)hi, CTRL, 0xF, 0xF, false);
    u64 nk = (((u64)nhi) << 32) | (u64)nlo;
    return nk < k ? nk : k;
}
__device__ __forceinline__ u64 wave_min64(u64 k) {
    k = dpp_min_step<0x111>(k); k = dpp_min_step<0x112>(k); k = dpp_min_step<0x114>(k);
    k = dpp_min_step<0x118>(k); k = dpp_min_step<0x142>(k); k = dpp_min_step<0x143>(k);
    unsigned lo = (unsigned)__builtin_amdgcn_readlane((int)(unsigned)k, 63);
    unsigned hi = (unsigned)__builtin_amdgcn_readlane((int)(unsigned)(k >> 32), 63);
    return (((u64)hi) << 32) | (u64)lo;
}
__device__ __forceinline__ float readlane_f(float v, int l) {
    return __int_as_float(__builtin_amdgcn_readlane(__float_as_int(v), l));
}

// ---------------- K0: G = K K^T and Pfx[t][s] = sum_{s'=s}^{t-1} G[t,s'] ----------------
__global__ __launch_bounds__(1024) void k0_gram(const float* __restrict__ K, float* __restrict__ G,
                                                float* __restrict__ Pfx) {
    __shared__ float Ks[BB][129];
    __shared__ float Gs[BB][BB];
    int tid = threadIdx.x;
    int s = tid & 63, tq = tid >> 6;
    float acc[4] = {0.f, 0.f, 0.f, 0.f};
    for (int d0 = 0; d0 < DD; d0 += 128) {
        #pragma unroll
        for (int i = 0; i < 8; ++i) {
            int e = i * 1024 + tid; int r = e >> 7, c = e & 127;
            Ks[r][c] = K[r * DD + d0 + c];
        }
        __syncthreads();
        for (int dl = 0; dl < 128; ++dl) {
            float kv = Ks[s][dl];
            #pragma unroll
            for (int i = 0; i < 4; ++i) acc[i] += Ks[tq * 4 + i][dl] * kv;
        }
        __syncthreads();
    }
    #pragma unroll
    for (int i = 0; i < 4; ++i) {
        G[(tq * 4 + i) * BB + s] = acc[i];
        Gs[tq * 4 + i][s] = acc[i];
    }
    __syncthreads();
    #pragma unroll
    for (int r = 0; r < 4; ++r) {
        int row = tq * 4 + r;
        float x = (s < row) ? Gs[row][s] : 0.f;
        #pragma unroll
        for (int o = 1; o < 64; o <<= 1) {
            float y = __shfl_down(x, o);
            if (s + o < 64) x += y;
        }
        Pfx[row * BB + s] = x;
    }
}

// ---------------- K1: S0p[half] = K @ MK0 over a 256-d half; n2p[half] = column sumsq ----------------
__global__ __launch_bounds__(256) void k1_s0(const float* __restrict__ K, const float* __restrict__ MK0,
                                             float* __restrict__ S0p, float* __restrict__ n2p) {
    __shared__ float Ks[64 * 65];
    __shared__ float Ms[64 * 65];
    __shared__ float sq[4 * 64];
    const int tid = threadIdx.x;
    const int lane = tid & 63, w = tid >> 6;
    const int jb = blockIdx.x * 64;
    const int dbase = blockIdx.y * 256;
    const int t4 = ((w << 2) | (lane >> 4)) << 2;
    const int jq0 = lane & 15;
    float acc[4][4];
    #pragma unroll
    for (int i = 0; i < 4; ++i)
        #pragma unroll
        for (int q = 0; q < 4; ++q) acc[i][q] = 0.f;
    float sqa = 0.f;
    for (int dt = 0; dt < 4; ++dt) {
        int d0 = dbase + dt * 64;
        #pragma unroll
        for (int i = 0; i < 16; ++i) {
            int e = i * 256 + tid; int r = e >> 6, c = e & 63;
            Ks[r * 65 + c] = K[r * DD + d0 + c];
            float m = MK0[(d0 + r) * MM + jb + c];
            Ms[r * 65 + c] = m;
            sqa += m * m;
        }
        __syncthreads();
        #pragma unroll 4
        for (int dl = 0; dl < 64; ++dl) {
            float kv[4], mv[4];
            #pragma unroll
            for (int i = 0; i < 4; ++i) kv[i] = Ks[(t4 + i) * 65 + dl];
            #pragma unroll
            for (int q = 0; q < 4; ++q) mv[q] = Ms[dl * 65 + jq0 + 16 * q];
            #pragma unroll
            for (int i = 0; i < 4; ++i)
                #pragma unroll
                for (int q = 0; q < 4; ++q) acc[i][q] += kv[i] * mv[q];
        }
        __syncthreads();
    }
    #pragma unroll
    for (int i = 0; i < 4; ++i)
        #pragma unroll
        for (int q = 0; q < 4; ++q)
            S0p[blockIdx.y * BB * MM + (t4 + i) * MM + jb + jq0 + 16 * q] = acc[i][q];
    sq[w * 64 + lane] = sqa;
    __syncthreads();
    if (w == 0) n2p[blockIdx.y * MM + jb + lane] =
        sq[lane] + sq[64 + lane] + sq[128 + lane] + sq[192 + lane];
}

// ---------------- K1b: cold-hypothesis E matrix ----------------
__global__ __launch_bounds__(256) void k1b_ecold(const float* __restrict__ S0p,
                                                 const float* __restrict__ G,
                                                 const float* __restrict__ Pfx,
                                                 const float* __restrict__ n2p,
                                                 const float* __restrict__ bp,
                                                 float* __restrict__ Ecold) {
    __shared__ float Pfx0s[BB], invks[BB], k2s[BB];
    int tid = threadIdx.x;
    int j = blockIdx.x * 256 + tid;
    if (tid < BB) {
        float g = G[tid * BB + tid];
        k2s[tid] = g;
        invks[tid] = __builtin_amdgcn_rsqf(g);
        Pfx0s[tid] = Pfx[tid * BB + 0];
    }
    const float beta = 1.f / (1.f + expf(-bp[0]));
    const float cuni = beta / (float)MM;
    float n2c = n2p[j] + n2p[MM + j];
    __syncthreads();
    for (int t = 0; t < BB; ++t) {
        float s0 = S0p[t * MM + j] + S0p[(BB + t) * MM + j];
        float d_ = s0 + cuni * Pfx0s[t];
        float cosv = d_ * invks[t] * __builtin_amdgcn_rsqf(n2c);
        float ee = __expf(cosv);
        Ecold[t * MM + j] = ee;
        n2c = n2c + 2.f * cuni * d_ + cuni * cuni * k2s[t];
    }
}

// ---------------- KS: Scold[t] = sum_j Ecold[t][j] ----------------
__global__ __launch_bounds__(256) void ks_rowsum(const float* __restrict__ Ecold, float* __restrict__ Scold) {
    __shared__ float sw[4];
    int t = blockIdx.x, tid = threadIdx.x;
    int lane = tid & 63, wid = tid >> 6;
    float s = 0.f;
    #pragma unroll
    for (int i = 0; i < 32; ++i) s += Ecold[t * MM + i * 256 + tid];
    #pragma unroll
    for (int o = 32; o > 0; o >>= 1) s += __shfl_down(s, o);
    if (lane == 0) sw[wid] = s;
    __syncthreads();
    if (tid == 0) Scold[t] = sw[0] + sw[1] + sw[2] + sw[3];
}

// ---------------- K2: 64-step scan; 4 waves; DPP reductions; slot-tracked hot w_u ----------------
__global__ __launch_bounds__(NT) void k2_scan(const float* __restrict__ Ecold,
                                              const float* __restrict__ G,
                                              const float* __restrict__ Pfx,
                                              const float* __restrict__ Scoldg,
                                              const float* __restrict__ bp,
                                              const float* __restrict__ gp,
                                              float* __restrict__ Etab_g,
                                              float* __restrict__ EcTab_g,
                                              float* __restrict__ Sg,
                                              float* __restrict__ invSg,
                                              int*   __restrict__ endTab_g,
                                              int*   __restrict__ hcolg) {
    __shared__ u64 red[2][4];
    __shared__ float EtabL[BB * BB];
    __shared__ float EcTabL[BB * BB];
    __shared__ float invSL[BB], SL[BB];
    __shared__ int endL[BB];

    const int tid = threadIdx.x;
    const int lane = tid & 63;
    const int wid = tid >> 6;

    const float beta  = 1.f / (1.f + expf(-bp[0]));
    const float gamma = gp[0];
    const float cuni  = beta / (float)MM;
    const float omb   = 1.f - beta;

    if (tid < BB) endL[tid] = BB;

    float wu[32];
    #pragma unroll
    for (int c = 0; c < 32; ++c) wu[c] = 0.f;

    float4 eb0[8], eb1[8];
    #pragma unroll
    for (int g = 0; g < 8; ++g) eb0[g] = *(const float4*)(Ecold + 4 * tid + 1024 * g);  // row 0
    float grow_c = G[lane], pfx_c = Pfx[lane];   // row t=0
    float Ssc_c = Scoldg[0];

    // lane-replicated slot state: slot s == lane, created at step s
    float slot_n2 = 0.f, slot_E = 0.f, slot_ec = 0.f, slot_ecpf = 0.f, wu_hot = 0.f;
    int   slot_j = -1;
    bool  slot_act = false;

    auto step = [&](int t, float4 (&cur)[8], float4 (&nxt)[8]) {
        // ---- 1. combine wave-partial argmins -> (j0, minval) ----
        int j0; float minval;
        if (t == 0) { j0 = 0; minval = 0.f; }
        else {
            u64 a0 = red[t & 1][0], a1 = red[t & 1][1], a2 = red[t & 1][2], a3 = red[t & 1][3];
            u64 m01 = a0 < a1 ? a0 : a1;
            u64 m23 = a2 < a3 ? a2 : a3;
            u64 mk  = m01 < m23 ? m01 : m23;
            j0 = (int)(mk & 0xFFFFFFFFu);
            minval = __uint_as_float((unsigned)(mk >> 32));
        }

        // ---- 2. prefetches for t+1 (drained by this step's barrier) ----
        if (t + 1 < BB) {
            #pragma unroll
            for (int g = 0; g < 8; ++g)
                nxt[g] = *(const float4*)(Ecold + (t + 1) * MM + 4 * tid + 1024 * g);
        }
        float grow_n = (t + 1 < BB) ? G[(t + 1) * BB + lane] : 0.f;
        float pfx_n  = (t + 1 < BB) ? Pfx[(t + 1) * BB + lane] : 0.f;
        float Ssc_n  = (t + 1 < BB) ? Scoldg[t + 1] : 0.f;
        float latev = 0.f;
        if (lane == t) latev = Ecold[t * MM + j0];

        const float k2t  = readlane_f(grow_c, t);    // G[t][t]
        const float invk = __builtin_amdgcn_rsqf(k2t);

        // ---- 3. supersession ballot (before slot t exists) ----
        u64 sup = __ballot(slot_act && (slot_j == j0));
        const bool has_sup = (sup != 0ull);
        const int  ssup = has_sup ? (int)__builtin_ctzll(sup) : 0;

        // ---- 4. hot slot update: pre-zero true e, Delta vs cold, n2 advance ----
        float myDelta = 0.f, e_true = 0.f;
        if (slot_act) {
            float d_ = cuni * pfx_c;                  // pfx_c = Pfx[t][lane], lane == lz
            if (lane >= 1) d_ += omb * grow_c;        // grow_c = G[t][lane]
            e_true = __expf(d_ * invk * __builtin_amdgcn_rsqf(slot_n2));
            myDelta = e_true - slot_ec;
            slot_E = e_true;
            slot_n2 = slot_n2 + 2.f * cuni * d_ + cuni * cuni * k2t;
        }

        // ---- 5. S, invS via DPP (identical in every wave: slot state is replicated) ----
        const float S = Ssc_c + wave_sum64(myDelta);
        const float invS = __builtin_amdgcn_rcpf(S);

        // ---- 6. slot w_u update (true hot w_u; spike lands on slot t-1 == j0prev) ----
        const float cuni_t = (t == 0) ? 0.f : cuni;
        if (slot_act) {
            float ww = cuni + ((t >= 2 && lane == t - 1) ? omb : 0.f);
            wu_hot = fmaf(gamma, wu_hot, fmaf(e_true, invS, ww));
        }

        // ---- 7. create slot t (fresh from argmin key, or takeover on supersession) ----
        float trans_wu = readlane_f(wu_hot, ssup);
        float trans_E  = readlane_f(e_true, ssup);
        if (lane == t) {
            slot_j = j0;
            float ww0 = cuni + ((t >= 1) ? omb : 0.f);
            slot_n2 = ww0 * ww0 * k2t;
            slot_act = true;
            slot_ec = latev;
            float fresh_wu = fmaf(gamma, minval, fmaf(latev, invS, cuni_t)); // bit-equal to cold owner's fma
            wu_hot = has_sup ? trans_wu : fresh_wu;
            slot_E = has_sup ? trans_E : latev;
        }
        if (has_sup) {
            if (lane == ssup) slot_act = false;
            if (wid == 0 && lane == t) endL[ssup] = t;
        }
        if (t + 1 < BB && slot_act) slot_ecpf = Ecold[(t + 1) * MM + slot_j];

        // ---- 8. phase C: cold w_u fma + min/idx over 32 cols (4 chains) ----
        float vmin[4]; int lmin[4];
        #pragma unroll
        for (int g = 0; g < 8; ++g) {
            float ev[4] = {cur[g].x, cur[g].y, cur[g].z, cur[g].w};
            #pragma unroll
            for (int q = 0; q < 4; ++q) {
                int c = g * 4 + q;
                float wun = fmaf(gamma, wu[c], fmaf(ev[q], invS, cuni_t));
                wu[c] = wun;
                if (g == 0) { vmin[q] = wun; lmin[q] = c; }
                else {
                    bool lt = wun < vmin[q];
                    vmin[q] = lt ? wun : vmin[q];
                    lmin[q] = lt ? c : lmin[q];
                }
            }
        }
        bool b1 = (vmin[1] < vmin[0]) || (vmin[1] == vmin[0] && lmin[1] < lmin[0]);
        float vA = b1 ? vmin[1] : vmin[0]; int cA = b1 ? lmin[1] : lmin[0];
        bool b3 = (vmin[3] < vmin[2]) || (vmin[3] == vmin[2] && lmin[3] < lmin[2]);
        float vBv = b3 ? vmin[3] : vmin[2]; int cB = b3 ? lmin[3] : lmin[2];
        bool b2 = (vBv < vA) || (vBv == vA && cB < cA);
        float vm = b2 ? vBv : vA; int cm = b2 ? cB : cA;
        int jmin = 4 * tid + ((cm >> 2) << 10) + (cm & 3);
        u64 key = (((u64)__float_as_uint(vm)) << 32) | (unsigned)jmin;

        // owner poisons its cold register for the newly-hot column (future steps via slot)
        if (((j0 & 1023) >> 2) == tid) {
            int cj = ((j0 >> 10) << 2) | (j0 & 3);
            #pragma unroll
            for (int c = 0; c < 32; ++c) if (c == cj) wu[c] = __builtin_inff();
        }

        // ---- 9. merge slot candidates, DPP min, publish wave partial ----
        u64 skey = slot_act ? ((((u64)__float_as_uint(wu_hot)) << 32) | (unsigned)slot_j) : ~0ull;
        key = skey < key ? skey : key;
        key = wave_min64(key);
        if (lane == 63) red[(t + 1) & 1][wid] = key;

        // ---- 10. log step state (LDS; dumped to global once at the end) ----
        if (wid == 0) {
            EtabL[t * BB + lane]  = slot_E;
            EcTabL[t * BB + lane] = slot_ec;
            if (lane == 0) { invSL[t] = invS; SL[t] = S; }
        }

        // ---- 11. advance ----
        if (slot_act) slot_ec = slot_ecpf;
        grow_c = grow_n; pfx_c = pfx_n; Ssc_c = Ssc_n;
        __syncthreads();
    };

    #pragma unroll 1
    for (int th = 0; th < BB; th += 2) {
        step(th, eb0, eb1);
        step(th + 1, eb1, eb0);
    }

    // epilogue: dump logs
    for (int i = tid; i < BB * BB; i += NT) {
        Etab_g[i]  = EtabL[i];
        EcTab_g[i] = EcTabL[i];
    }
    if (tid < BB) {
        Sg[tid] = SL[tid];
        invSg[tid] = invSL[tid];
        endTab_g[tid] = endL[tid];
    }
    if (wid == 0) hcolg[lane] = slot_j;
}

// ---------------- K3: parts[jslice][t][d] = sum_{j in slice} Ecold[t,j] * MK0[d,j] ----------------
__global__ __launch_bounds__(256) void k3_u1(const float* __restrict__ Ecold, const float* __restrict__ MK0,
                                             float* __restrict__ parts) {
    __shared__ float Ws[64 * 65];
    __shared__ float Msub[64 * 65];
    const int tid = threadIdx.x;
    const int lane = tid & 63, w = tid >> 6;
    const int d0 = blockIdx.x * 64;
    const int by = blockIdx.y;
    const int t4 = ((w << 2) | (lane >> 4)) << 2;
    const int dq0 = lane & 15;
    float acc[4][4];
    #pragma unroll
    for (int i = 0; i < 4; ++i)
        #pragma unroll
        for (int q = 0; q < 4; ++q) acc[i][q] = 0.f;
    for (int sub = 0; sub < 4; ++sub) {
        int jb = by * 256 + sub * 64;
        #pragma unroll
        for (int i = 0; i < 16; ++i) {
            int e = i * 256 + tid; int r = e >> 6, c = e & 63;
            Ws[r * 65 + c] = Ecold[r * MM + jb + c];
            Msub[r * 65 + c] = MK0[(d0 + r) * MM + jb + c];
        }
        __syncthreads();
        #pragma unroll 4
        for (int jl = 0; jl < 64; ++jl) {
            float wv[4], mv[4];
            #pragma unroll
            for (int i = 0; i < 4; ++i) wv[i] = Ws[(t4 + i) * 65 + jl];
            #pragma unroll
            for (int q = 0; q < 4; ++q) mv[q] = Msub[(dq0 + 16 * q) * 65 + jl];
            #pragma unroll
            for (int i = 0; i < 4; ++i)
                #pragma unroll
                for (int q = 0; q < 4; ++q) acc[i][q] += wv[i] * mv[q];
        }
        __syncthreads();
    }
    #pragma unroll
    for (int i = 0; i < 4; ++i)
        #pragma unroll
        for (int q = 0; q < 4; ++q)
            parts[(by * 64 + t4 + i) * DD + d0 + dq0 + 16 * q] = acc[i][q];
}

// ---------------- K3b: gather hot columns of MK0 into MKhot[s][d] ----------------
__global__ __launch_bounds__(512) void k3b_gather(const float* __restrict__ MK0, const int* __restrict__ hcolg,
                                                  float* __restrict__ MKhot) {
    int i = blockIdx.x, d = threadIdx.x;
    int h = hcolg[i];
    MKhot[i * DD + d] = MK0[d * MM + h];
}

// ---------------- K4: rebuild A/Dcol rows (R4 step-7 arithmetic) + final combine ----------------
__global__ __launch_bounds__(512) void k4_final(const float* __restrict__ parts,
                                                const float* __restrict__ K,
                                                const float* __restrict__ Etab,
                                                const float* __restrict__ EcTab,
                                                const int*   __restrict__ endTab,
                                                const float* __restrict__ Sg,
                                                const float* __restrict__ invSg,
                                                const float* __restrict__ MKhot,
                                                const float* __restrict__ bp,
                                                float* __restrict__ out) {
    __shared__ float Arow[BB];
    __shared__ float Drow[BB];
    int t = blockIdx.x, d = threadIdx.x;
    if (d < BB) {
        const float beta = 1.f / (1.f + expf(-bp[0]));
        const float cuni = beta / (float)MM;
        const float omb  = 1.f - beta;
        int s = d;
        float Ev = Etab[t * BB + s];
        int endv = endTab[s];
        bool act = (s <= t) && (t < endv);
        float S = Sg[t], invS = invSg[t];
        float ev = act ? Ev : 0.f;
        float x = ev;
        #pragma unroll
        for (int o = 1; o < 64; o <<= 1) {
            float y = __shfl_down(x, o);
            if (s + o < 64) x += y;
        }
        float suf = x - ev;
        float arow = 0.f;
        if (s < t) {
            float Qe = S - suf;
            arow = cuni * Qe;
            if (s >= 1 && act) arow += omb * Ev;
            arow *= invS;
        }
        Arow[s] = arow;
        Drow[s] = act ? (-invS * EcTab[t * BB + s]) : 0.f;
    }
    __syncthreads();
    float isv = invSg[t];
    float s1 = 0.f;
    #pragma unroll
    for (int p = 0; p < 32; ++p) s1 += parts[(p * 64 + t) * DD + d];
    float s2 = 0.f;
    for (int i = 0; i < BB; ++i) s2 += Drow[i] * MKhot[i * DD + d];
    float s3 = 0.f;
    for (int i = 0; i < BB; ++i) s3 += Arow[i] * K[i * DD + d];
    out[t * DD + d] = isv * s1 + s2 + s3;
}

extern "C" void kernel_launch(void* const* d_in, const int* in_sizes, int n_in,
                              void* d_out, int out_size, void* d_ws, size_t ws_size,
                              hipStream_t stream) {
    const float* K   = (const float*)d_in[0];   // k: [B,1,D]
    // d_in[1] = u: unused (MU never read for the output)
    const float* MK0 = (const float*)d_in[2];   // memory_knowledge: [D,M]
    // d_in[3] = memory_understanding: unused
    const float* bp  = (const float*)d_in[4];   // beta_param
    const float* gp  = (const float*)d_in[5];   // memory_gamma

    float* ws    = (float*)d_ws;
    float* G     = ws;                  // 4096
    float* Pfx   = G + 4096;            // 4096
    float* S0p   = Pfx + 4096;          // 2*64*8192 = 1048576
    float* n2p   = S0p + 1048576;       // 16384
    float* Ecold = n2p + 16384;         // 524288
    float* Scold = Ecold + 524288;      // 64
    float* Etab  = Scold + 64;          // 4096
    float* EcTab = Etab + 4096;         // 4096
    float* Sarr  = EcTab + 4096;        // 64
    float* invS  = Sarr + 64;           // 64
    float* MKhot = invS + 64;           // 32768
    float* parts = MKhot + 32768;       // 32*64*512 = 1048576
    int*   hcol  = (int*)(parts + 1048576);  // 64
    int*   endT  = hcol + 64;                // 64
    float* out   = (float*)d_out;       // [B,1,D] f32

    k0_gram   <<<1, 1024, 0, stream>>>(K, G, Pfx);
    k1_s0     <<<dim3(128, 2), 256, 0, stream>>>(K, MK0, S0p, n2p);
    k1b_ecold <<<32, 256, 0, stream>>>(S0p, G, Pfx, n2p, bp, Ecold);
    ks_rowsum <<<64, 256, 0, stream>>>(Ecold, Scold);
    k2_scan   <<<1, NT, 0, stream>>>(Ecold, G, Pfx, Scold, bp, gp, Etab, EcTab, Sarr, invS, endT, hcol);
    k3_u1     <<<dim3(8, 32), 256, 0, stream>>>(Ecold, MK0, parts);
    k3b_gather<<<64, 512, 0, stream>>>(MK0, hcol, MKhot);
    k4_final  <<<64, 512, 0, stream>>>(parts, K, Etab, EcTab, endT, Sarr, invS, MKhot, bp, out);
}

// Round 7
// 287.059 us; speedup vs baseline: 1.3093x; 1.3093x over previous
//
#include <hip/hip_runtime.h>
#include <math.h>

#define BB 64
#define DD 512
#define MM 8192
#define TPB 1024
#define CPT 8   // MM / TPB cold columns per thread

typedef unsigned long long u64;

// ---------------- DPP wave-64 primitives ----------------
template<int CTRL>
__device__ __forceinline__ float dpp_addf(float x) {
    int y = __builtin_amdgcn_update_dpp(0, __float_as_int(x), CTRL, 0xF, 0xF, true);
    return x + __int_as_float(y);
}
__device__ __forceinline__ float wave_sum64(float x) {
    x = dpp_addf<0x111>(x); x = dpp_addf<0x112>(x); x = dpp_addf<0x114>(x); x = dpp_addf<0x118>(x);
    x = dpp_addf<0x142>(x); x = dpp_addf<0x143>(x);
    return __int_as_float(__builtin_amdgcn_readlane(__float_as_int(x), 63));
}
template<int CTRL>
__device__ __forceinline__ u64 dpp_min_step(u64 k) {
    unsigned lo = (unsigned)k, hi = (unsigned)(k >> 32);
    unsigned nlo = (unsigned)__builtin_amdgcn_update_dpp((int)0xFFFFFFFFu, (int)lo, CTRL, 0xF, 0xF, false);
    unsigned nhi = (unsigned)__builtin_amdgcn_update_dpp((int)0xFFFFFFFFu, (int)hi, CTRL, 0xF, 0xF, false);
    u64 nk = (((u64)nhi) << 32) | (u64)nlo;
    return nk < k ? nk : k;
}
__device__ __forceinline__ u64 wave_min64(u64 k) {
    k = dpp_min_step<0x111>(k); k = dpp_min_step<0x112>(k); k = dpp_min_step<0x114>(k);
    k = dpp_min_step<0x118>(k); k = dpp_min_step<0x142>(k); k = dpp_min_step<0x143>(k);
    unsigned lo = (unsigned)__builtin_amdgcn_readlane((int)(unsigned)k, 63);
    unsigned hi = (unsigned)__builtin_amdgcn_readlane((int)(unsigned)(k >> 32), 63);
    return (((u64)hi) << 32) | (u64)lo;
}
__device__ __forceinline__ float readlane_f(float v, int l) {
    return __int_as_float(__builtin_amdgcn_readlane(__float_as_int(v), l));
}

// ---------------- K0: G = K K^T and Pfx[t][s] = sum_{s'=s}^{t-1} G[t,s'] ----------------
__global__ __launch_bounds__(1024) void k0_gram(const float* __restrict__ K, float* __restrict__ G,
                                                float* __restrict__ Pfx) {
    __shared__ float Ks[BB][129];
    __shared__ float Gs[BB][BB];
    int tid = threadIdx.x;
    int s = tid & 63, tq = tid >> 6;
    float acc[4] = {0.f, 0.f, 0.f, 0.f};
    for (int d0 = 0; d0 < DD; d0 += 128) {
        #pragma unroll
        for (int i = 0; i < 8; ++i) {
            int e = i * 1024 + tid; int r = e >> 7, c = e & 127;
            Ks[r][c] = K[r * DD + d0 + c];
        }
        __syncthreads();
        for (int dl = 0; dl < 128; ++dl) {
            float kv = Ks[s][dl];
            #pragma unroll
            for (int i = 0; i < 4; ++i) acc[i] += Ks[tq * 4 + i][dl] * kv;
        }
        __syncthreads();
    }
    #pragma unroll
    for (int i = 0; i < 4; ++i) {
        G[(tq * 4 + i) * BB + s] = acc[i];
        Gs[tq * 4 + i][s] = acc[i];
    }
    __syncthreads();
    #pragma unroll
    for (int r = 0; r < 4; ++r) {
        int row = tq * 4 + r;
        float x = (s < row) ? Gs[row][s] : 0.f;
        #pragma unroll
        for (int o = 1; o < 64; o <<= 1) {
            float y = __shfl_down(x, o);
            if (s + o < 64) x += y;
        }
        Pfx[row * BB + s] = x;
    }
}

// ---------------- K1: S0p[half] = K @ MK0 over a 256-d half; n2p[half] = column sumsq ----------------
__global__ __launch_bounds__(256) void k1_s0(const float* __restrict__ K, const float* __restrict__ MK0,
                                             float* __restrict__ S0p, float* __restrict__ n2p) {
    __shared__ float Ks[64 * 65];
    __shared__ float Ms[64 * 65];
    __shared__ float sq[4 * 64];
    const int tid = threadIdx.x;
    const int lane = tid & 63, w = tid >> 6;
    const int jb = blockIdx.x * 64;
    const int dbase = blockIdx.y * 256;
    const int t4 = ((w << 2) | (lane >> 4)) << 2;
    const int jq0 = lane & 15;
    float acc[4][4];
    #pragma unroll
    for (int i = 0; i < 4; ++i)
        #pragma unroll
        for (int q = 0; q < 4; ++q) acc[i][q] = 0.f;
    float sqa = 0.f;
    for (int dt = 0; dt < 4; ++dt) {
        int d0 = dbase + dt * 64;
        #pragma unroll
        for (int i = 0; i < 16; ++i) {
            int e = i * 256 + tid; int r = e >> 6, c = e & 63;
            Ks[r * 65 + c] = K[r * DD + d0 + c];
            float m = MK0[(d0 + r) * MM + jb + c];
            Ms[r * 65 + c] = m;
            sqa += m * m;
        }
        __syncthreads();
        #pragma unroll 4
        for (int dl = 0; dl < 64; ++dl) {
            float kv[4], mv[4];
            #pragma unroll
            for (int i = 0; i < 4; ++i) kv[i] = Ks[(t4 + i) * 65 + dl];
            #pragma unroll
            for (int q = 0; q < 4; ++q) mv[q] = Ms[dl * 65 + jq0 + 16 * q];
            #pragma unroll
            for (int i = 0; i < 4; ++i)
                #pragma unroll
                for (int q = 0; q < 4; ++q) acc[i][q] += kv[i] * mv[q];
        }
        __syncthreads();
    }
    #pragma unroll
    for (int i = 0; i < 4; ++i)
        #pragma unroll
        for (int q = 0; q < 4; ++q)
            S0p[blockIdx.y * BB * MM + (t4 + i) * MM + jb + jq0 + 16 * q] = acc[i][q];
    sq[w * 64 + lane] = sqa;
    __syncthreads();
    if (w == 0) n2p[blockIdx.y * MM + jb + lane] =
        sq[lane] + sq[64 + lane] + sq[128 + lane] + sq[192 + lane];
}

// ---------------- K1b: cold-hypothesis E matrix ----------------
__global__ __launch_bounds__(256) void k1b_ecold(const float* __restrict__ S0p,
                                                 const float* __restrict__ G,
                                                 const float* __restrict__ Pfx,
                                                 const float* __restrict__ n2p,
                                                 const float* __restrict__ bp,
                                                 float* __restrict__ Ecold) {
    __shared__ float Pfx0s[BB], invks[BB], k2s[BB];
    int tid = threadIdx.x;
    int j = blockIdx.x * 256 + tid;
    if (tid < BB) {
        float g = G[tid * BB + tid];
        k2s[tid] = g;
        invks[tid] = __builtin_amdgcn_rsqf(g);
        Pfx0s[tid] = Pfx[tid * BB + 0];
    }
    const float beta = 1.f / (1.f + expf(-bp[0]));
    const float cuni = beta / (float)MM;
    float n2c = n2p[j] + n2p[MM + j];
    __syncthreads();
    for (int t = 0; t < BB; ++t) {
        float s0 = S0p[t * MM + j] + S0p[(BB + t) * MM + j];
        float d_ = s0 + cuni * Pfx0s[t];
        float cosv = d_ * invks[t] * __builtin_amdgcn_rsqf(n2c);
        float ee = __expf(cosv);
        Ecold[t * MM + j] = ee;
        n2c = n2c + 2.f * cuni * d_ + cuni * cuni * k2s[t];
    }
}

// ---------------- KS: Scold[t] = sum_j Ecold[t][j] ----------------
__global__ __launch_bounds__(256) void ks_rowsum(const float* __restrict__ Ecold, float* __restrict__ Scold) {
    __shared__ float sw[4];
    int t = blockIdx.x, tid = threadIdx.x;
    int lane = tid & 63, wid = tid >> 6;
    float s = 0.f;
    #pragma unroll
    for (int i = 0; i < 32; ++i) s += Ecold[t * MM + i * 256 + tid];
    #pragma unroll
    for (int o = 32; o > 0; o >>= 1) s += __shfl_down(s, o);
    if (lane == 0) sw[wid] = s;
    __syncthreads();
    if (tid == 0) Scold[t] = sw[0] + sw[1] + sw[2] + sw[3];
}

// ---------------- K2: 64-step scan; 16 waves, 8 cols/thread, DPP reductions, 1 barrier/step ----------------
// Arithmetic lifted verbatim from the R5 leader (passing): per-wave replicated slot state,
// cold fma + poison-after-phase-C, exact (value,index) min combine -> bit-identical trajectory.
__global__ __launch_bounds__(1024) void k2_scan(const float* __restrict__ Ecold,
                                                const float* __restrict__ G,
                                                const float* __restrict__ Pfx,
                                                const float* __restrict__ Scoldg,
                                                const float* __restrict__ bp,
                                                const float* __restrict__ gp,
                                                float* __restrict__ Etab_g,
                                                float* __restrict__ EcTab_g,
                                                float* __restrict__ Sg,
                                                float* __restrict__ invSg,
                                                int*   __restrict__ endTab_g,
                                                int*   __restrict__ hcolg) {
    __shared__ u64 red[2][16];       // double-buffered wave-partial argmins
    __shared__ float EtabL[BB * BB];
    __shared__ float EcTabL[BB * BB];
    __shared__ float invSL[BB], SL[BB];
    __shared__ int endL[BB];

    const int tid = threadIdx.x;
    const int lane = tid & 63;
    const int wid = tid >> 6;

    const float beta  = 1.f / (1.f + expf(-bp[0]));
    const float gamma = gp[0];
    const float cuni  = beta / (float)MM;
    const float omb   = 1.f - beta;

    if (tid < BB) endL[tid] = BB;

    // cold state: 8 columns/thread {c*1024 + tid}; prefetch registers ping-pong
    float wu[CPT], eb0[CPT], eb1[CPT];
    #pragma unroll
    for (int c = 0; c < CPT; ++c) {
        wu[c] = 0.f;
        eb0[c] = Ecold[c * TPB + tid];       // row t=0
    }

    // lane-replicated slot state (identical in every wave): slot s == lane, created at step s
    float slot_n2 = 0.f, slot_E = 0.f, slot_ec = 0.f, slot_ecpf = 0.f, wu_hot = 0.f;
    int   slot_j = -1;
    bool  slot_act = false;

    float grow_c = G[lane], pfx_c = Pfx[lane];   // row t=0
    float Ssc_c = Scoldg[0];
    __syncthreads();

    auto step = [&](int t, float (&cur)[CPT], float (&nxt)[CPT]) {
        // ---- 1. combine 16 wave-partial argmins -> (j0, minval), per wave via DPP ----
        int j0; float minval;
        if (t == 0) { j0 = 0; minval = 0.f; }
        else {
            u64 pm = red[t & 1][lane & 15];
            pm = wave_min64(pm);
            j0 = (int)(pm & 0xFFFFFFFFu);
            minval = __uint_as_float((unsigned)(pm >> 32));
        }

        // ---- 2. prefetch t+1 (drained by this step's barrier) ----
        if (t + 1 < BB) {
            #pragma unroll
            for (int c = 0; c < CPT; ++c) nxt[c] = Ecold[(t + 1) * MM + c * TPB + tid];
        }
        float grow_n = (t + 1 < BB) ? G[(t + 1) * BB + lane] : 0.f;
        float pfx_n  = (t + 1 < BB) ? Pfx[(t + 1) * BB + lane] : 0.f;
        float Ssc_n  = (t + 1 < BB) ? Scoldg[t + 1] : 0.f;
        float latev = 0.f;
        if (lane == t) latev = Ecold[t * MM + j0];

        const float k2t  = readlane_f(grow_c, t);    // G[t][t]
        const float invk = __builtin_amdgcn_rsqf(k2t);

        // ---- 3. supersession ballot (before slot t exists) ----
        u64 sup = __ballot(slot_act && (slot_j == j0));
        const bool has_sup = (sup != 0ull);
        const int  ssup = has_sup ? (int)__builtin_ctzll(sup) : 0;

        // ---- 4. hot slot update: pre-zero true e, Delta vs cold, n2 advance ----
        float myDelta = 0.f, e_true = 0.f;
        if (slot_act) {
            float d_ = cuni * pfx_c;                  // pfx_c = Pfx[t][lane], lane == lz
            if (lane >= 1) d_ += omb * grow_c;        // grow_c = G[t][lane]
            e_true = __expf(d_ * invk * __builtin_amdgcn_rsqf(slot_n2));
            myDelta = e_true - slot_ec;
            slot_E = e_true;
            slot_n2 = slot_n2 + 2.f * cuni * d_ + cuni * cuni * k2t;
        }

        // ---- 5. S, invS (identical in every wave) ----
        const float S = Ssc_c + wave_sum64(myDelta);
        const float invS = __builtin_amdgcn_rcpf(S);
        const float cuni_t = (t == 0) ? 0.f : cuni;

        // ---- 6. slot w_u update (spike lands on slot t-1 == j0prev) ----
        if (slot_act) {
            float ww = cuni + ((t >= 2 && lane == t - 1) ? omb : 0.f);
            wu_hot = fmaf(gamma, wu_hot, fmaf(e_true, invS, ww));
        }

        // ---- 7. create slot t (fresh from argmin key, or takeover on supersession) ----
        float trans_wu = readlane_f(wu_hot, ssup);
        float trans_E  = readlane_f(e_true, ssup);
        if (lane == t) {
            slot_j = j0;
            float ww0 = cuni + ((t >= 1) ? omb : 0.f);
            slot_n2 = ww0 * ww0 * k2t;
            slot_act = true;
            slot_ec = latev;
            float fresh_wu = fmaf(gamma, minval, fmaf(latev, invS, cuni_t)); // bit-equal to cold owner's fma
            wu_hot = has_sup ? trans_wu : fresh_wu;
            slot_E = has_sup ? trans_E : latev;
        }
        if (has_sup) {
            if (lane == ssup) slot_act = false;
            if (wid == 0 && lane == t) endL[ssup] = t;
        }
        if (t + 1 < BB && slot_act) slot_ecpf = Ecold[(t + 1) * MM + slot_j];

        // ---- 8. phase C: cold w_u fma + first-index min over 8 cols ----
        float vmin = 0.f; int jmin = 0;
        #pragma unroll
        for (int c = 0; c < CPT; ++c) {
            float wun = fmaf(gamma, wu[c], fmaf(cur[c], invS, cuni_t));
            wu[c] = wun;
            int j = c * TPB + tid;
            if (c == 0) { vmin = wun; jmin = j; }
            else if (wun < vmin) { vmin = wun; jmin = j; }   // ascending j: strict < = first-index
        }
        u64 key = (((u64)__float_as_uint(vmin)) << 32) | (unsigned)jmin;

        // owner poisons its cold register for the newly-hot column (future steps via slot)
        if ((j0 & (TPB - 1)) == tid) {
            int cj = j0 >> 10;
            #pragma unroll
            for (int c = 0; c < CPT; ++c) if (c == cj) wu[c] = __builtin_inff();
        }

        // ---- 9. merge slot candidates, DPP wave min, publish wave partial ----
        u64 skey = slot_act ? ((((u64)__float_as_uint(wu_hot)) << 32) | (unsigned)slot_j) : ~0ull;
        key = skey < key ? skey : key;
        key = wave_min64(key);
        if (lane == 0) red[(t + 1) & 1][wid] = key;

        // ---- 10. log step state (wave 0; dumped to global at the end) ----
        if (wid == 0) {
            EtabL[t * BB + lane]  = slot_E;
            EcTabL[t * BB + lane] = slot_ec;
            if (lane == 0) { invSL[t] = invS; SL[t] = S; }
        }

        // ---- 11. advance ----
        if (slot_act) slot_ec = slot_ecpf;
        grow_c = grow_n; pfx_c = pfx_n; Ssc_c = Ssc_n;
        __syncthreads();                 // the ONE barrier: drains prefetches, publishes red[]
    };

    #pragma unroll 1
    for (int th = 0; th < BB; th += 2) {
        step(th, eb0, eb1);
        step(th + 1, eb1, eb0);
    }

    // epilogue: dump logs
    for (int i = tid; i < BB * BB; i += TPB) {
        Etab_g[i]  = EtabL[i];
        EcTab_g[i] = EcTabL[i];
    }
    if (tid < BB) {
        Sg[tid] = SL[tid];
        invSg[tid] = invSL[tid];
        endTab_g[tid] = endL[tid];
    }
    if (wid == 0) hcolg[lane] = slot_j;
}

// ---------------- K3: parts[jslice][t][d] = sum_{j in slice} Ecold[t,j] * MK0[d,j] ----------------
__global__ __launch_bounds__(256) void k3_u1(const float* __restrict__ Ecold, const float* __restrict__ MK0,
                                             float* __restrict__ parts) {
    __shared__ float Ws[64 * 65];
    __shared__ float Msub[64 * 65];
    const int tid = threadIdx.x;
    const int lane = tid & 63, w = tid >> 6;
    const int d0 = blockIdx.x * 64;
    const int by = blockIdx.y;
    const int t4 = ((w << 2) | (lane >> 4)) << 2;
    const int dq0 = lane & 15;
    float acc[4][4];
    #pragma unroll
    for (int i = 0; i < 4; ++i)
        #pragma unroll
        for (int q = 0; q < 4; ++q) acc[i][q] = 0.f;
    for (int sub = 0; sub < 4; ++sub) {
        int jb = by * 256 + sub * 64;
        #pragma unroll
        for (int i = 0; i < 16; ++i) {
            int e = i * 256 + tid; int r = e >> 6, c = e & 63;
            Ws[r * 65 + c] = Ecold[r * MM + jb + c];
            Msub[r * 65 + c] = MK0[(d0 + r) * MM + jb + c];
        }
        __syncthreads();
        #pragma unroll 4
        for (int jl = 0; jl < 64; ++jl) {
            float wv[4], mv[4];
            #pragma unroll
            for (int i = 0; i < 4; ++i) wv[i] = Ws[(t4 + i) * 65 + jl];
            #pragma unroll
            for (int q = 0; q < 4; ++q) mv[q] = Msub[(dq0 + 16 * q) * 65 + jl];
            #pragma unroll
            for (int i = 0; i < 4; ++i)
                #pragma unroll
                for (int q = 0; q < 4; ++q) acc[i][q] += wv[i] * mv[q];
        }
        __syncthreads();
    }
    #pragma unroll
    for (int i = 0; i < 4; ++i)
        #pragma unroll
        for (int q = 0; q < 4; ++q)
            parts[(by * 64 + t4 + i) * DD + d0 + dq0 + 16 * q] = acc[i][q];
}

// ---------------- K3b: gather hot columns of MK0 into MKhot[s][d] ----------------
__global__ __launch_bounds__(512) void k3b_gather(const float* __restrict__ MK0, const int* __restrict__ hcolg,
                                                  float* __restrict__ MKhot) {
    int i = blockIdx.x, d = threadIdx.x;
    int h = hcolg[i];
    MKhot[i * DD + d] = MK0[d * MM + h];
}

// ---------------- K4: rebuild A/Dcol rows + final combine ----------------
__global__ __launch_bounds__(512) void k4_final(const float* __restrict__ parts,
                                                const float* __restrict__ K,
                                                const float* __restrict__ Etab,
                                                const float* __restrict__ EcTab,
                                                const int*   __restrict__ endTab,
                                                const float* __restrict__ Sg,
                                                const float* __restrict__ invSg,
                                                const float* __restrict__ MKhot,
                                                const float* __restrict__ bp,
                                                float* __restrict__ out) {
    __shared__ float Arow[BB];
    __shared__ float Drow[BB];
    int t = blockIdx.x, d = threadIdx.x;
    if (d < BB) {
        const float beta = 1.f / (1.f + expf(-bp[0]));
        const float cuni = beta / (float)MM;
        const float omb  = 1.f - beta;
        int s = d;
        float Ev = Etab[t * BB + s];
        int endv = endTab[s];
        bool act = (s <= t) && (t < endv);
        float S = Sg[t], invS = invSg[t];
        float ev = act ? Ev : 0.f;
        float x = ev;
        #pragma unroll
        for (int o = 1; o < 64; o <<= 1) {
            float y = __shfl_down(x, o);
            if (s + o < 64) x += y;
        }
        float suf = x - ev;
        float arow = 0.f;
        if (s < t) {
            float Qe = S - suf;
            arow = cuni * Qe;
            if (s >= 1 && act) arow += omb * Ev;
            arow *= invS;
        }
        Arow[s] = arow;
        Drow[s] = act ? (-invS * EcTab[t * BB + s]) : 0.f;
    }
    __syncthreads();
    float isv = invSg[t];
    float s1 = 0.f;
    #pragma unroll
    for (int p = 0; p < 32; ++p) s1 += parts[(p * 64 + t) * DD + d];
    float s2 = 0.f;
    for (int i = 0; i < BB; ++i) s2 += Drow[i] * MKhot[i * DD + d];
    float s3 = 0.f;
    for (int i = 0; i < BB; ++i) s3 += Arow[i] * K[i * DD + d];
    out[t * DD + d] = isv * s1 + s2 + s3;
}

extern "C" void kernel_launch(void* const* d_in, const int* in_sizes, int n_in,
                              void* d_out, int out_size, void* d_ws, size_t ws_size,
                              hipStream_t stream) {
    const float* K   = (const float*)d_in[0];   // k: [B,1,D]
    // d_in[1] = u: unused (MU never read for the output)
    const float* MK0 = (const float*)d_in[2];   // memory_knowledge: [D,M]
    // d_in[3] = memory_understanding: unused
    const float* bp  = (const float*)d_in[4];   // beta_param
    const float* gp  = (const float*)d_in[5];   // memory_gamma

    float* ws    = (float*)d_ws;
    float* G     = ws;                  // 4096
    float* Pfx   = G + 4096;            // 4096
    float* S0p   = Pfx + 4096;          // 2*64*8192 = 1048576
    float* n2p   = S0p + 1048576;       // 16384
    float* Ecold = n2p + 16384;         // 524288
    float* Scold = Ecold + 524288;      // 64
    float* Etab  = Scold + 64;          // 4096
    float* EcTab = Etab + 4096;         // 4096
    float* Sarr  = EcTab + 4096;        // 64
    float* invS  = Sarr + 64;           // 64
    float* MKhot = invS + 64;           // 32768
    float* parts = MKhot + 32768;       // 32*64*512 = 1048576
    int*   hcol  = (int*)(parts + 1048576);  // 64
    int*   endT  = hcol + 64;                // 64
    float* out   = (float*)d_out;       // [B,1,D] f32

    k0_gram   <<<1, 1024, 0, stream>>>(K, G, Pfx);
    k1_s0     <<<dim3(128, 2), 256, 0, stream>>>(K, MK0, S0p, n2p);
    k1b_ecold <<<32, 256, 0, stream>>>(S0p, G, Pfx, n2p, bp, Ecold);
    ks_rowsum <<<64, 256, 0, stream>>>(Ecold, Scold);
    k2_scan   <<<1, 1024, 0, stream>>>(Ecold, G, Pfx, Scold, bp, gp,
                                       Etab, EcTab, Sarr, invS, endT, hcol);
    k3_u1     <<<dim3(8, 32), 256, 0, stream>>>(Ecold, MK0, parts);
    k3b_gather<<<64, 512, 0, stream>>>(MK0, hcol, MKhot);
    k4_final  <<<64, 512, 0, stream>>>(parts, K, Etab, EcTab, endT, Sarr, invS, MKhot, bp, out);
}